// Round 3
// baseline (497.370 us; speedup 1.0000x reference)
//
#include <hip/hip_runtime.h>
#include <cstdint>
#include <cstddef>

// ---------------- problem constants (fixed by setup_inputs) ----------------
#define Cc   512        // channels
#define Tt   16         // temporal length
#define HWn  1024       // h*w = 32*32
#define NBat 2          // batch
#define Mtot (NBat*Tt*HWn)   // 32768 sequence rows
#define Hh   8          // heads
#define CHd  64         // head dim
#define NQKV 1536       // 3*C

typedef _Float16 half8  __attribute__((ext_vector_type(8)));
typedef _Float16 half2t __attribute__((ext_vector_type(2)));
typedef float    f32x4  __attribute__((ext_vector_type(4)));

// async global->LDS, 16B per lane; LDS dest = wave-uniform base + lane*16
__device__ __forceinline__ void gl_lds16(const void* g, void* l) {
  __builtin_amdgcn_global_load_lds(
      (const __attribute__((address_space(1))) unsigned int*)g,
      (__attribute__((address_space(3))) unsigned int*)l, 16, 0, 0);
}

__device__ __forceinline__ float fdot2h(half2t a, half2t b, float c) {
#if __has_builtin(__builtin_amdgcn_fdot2)
  return __builtin_amdgcn_fdot2(a, b, c, false);
#else
  return c + (float)a[0] * (float)b[0] + (float)a[1] * (float)b[1];
#endif
}

// ---------------- K0: weights fp32 -> fp16 ----------------
__global__ __launch_bounds__(256) void wconv_k(const float* __restrict__ qw,
                                               const float* __restrict__ pw,
                                               _Float16* __restrict__ wq,
                                               _Float16* __restrict__ wp) {
  int i = blockIdx.x * 256 + threadIdx.x;
  if (i < NQKV * Cc) wq[i] = (_Float16)qw[i];
  if (i < Cc * Cc)   wp[i] = (_Float16)pw[i];
}

// ---------------- K1: LayerNorm -> Ahat fp16 [M][512] ----------------
__global__ __launch_bounds__(256) void ln_k(const float* __restrict__ x,
                                            const float* __restrict__ g,
                                            const float* __restrict__ bln,
                                            _Float16* __restrict__ Ah) {
  int blk = blockIdx.x;                       // 128 blocks
  int bi = blk >> 6, ti = (blk >> 2) & 15, hwc = blk & 3;
  int t = threadIdx.x;
  int hw = hwc * 256 + t;
  const float* xp = x + ((size_t)bi * Cc * Tt + ti) * HWn + hw;
  float s = 0.f, s2 = 0.f;
  #pragma unroll 8
  for (int ci = 0; ci < Cc; ++ci) {
    float v = xp[(size_t)ci * (Tt * HWn)];
    s += v; s2 += v * v;
  }
  float mean = s * (1.f / Cc);
  float var  = s2 * (1.f / Cc) - mean * mean;
  float rs   = rsqrtf(var + 1e-5f);
  size_t m = ((size_t)(bi * Tt + ti)) * HWn + hw;
  _Float16* dst = Ah + m * Cc;
  for (int k0 = 0; k0 < Cc; k0 += 8) {
    half8 hv;
    #pragma unroll
    for (int u = 0; u < 8; ++u) {
      int ci = k0 + u;
      float v = xp[(size_t)ci * (Tt * HWn)];
      hv[u] = (_Float16)((v - mean) * rs * g[ci] + bln[ci]);
    }
    *(half8*)(dst + k0) = hv;
  }
}

// ---------------- K2/K4: fp16 MFMA GEMM (triple-buffered, swizzled) -------
template<int NCOLS, bool PROJ>
__global__ __launch_bounds__(256) void gemm_k(const _Float16* __restrict__ A,
                                              const _Float16* __restrict__ W,
                                              const float* __restrict__ bias,
                                              _Float16* __restrict__ Cout,
                                              const float* __restrict__ xres,
                                              float* __restrict__ outF) {
  __shared__ union {
    struct { _Float16 A[3][128 * 32]; _Float16 B[3][128 * 32]; } s;  // 48 KB
    float Cs[64 * 129];
  } u;

  const int tid  = threadIdx.x;
  const int wave = tid >> 6, lane = tid & 63;
  const int NTN = NCOLS / 128;
  const int tile_m = blockIdx.x / NTN;
  const int tile_n = blockIdx.x % NTN;
  const int m0 = tile_m * 128, n0 = tile_n * 128;
  const int wm = wave >> 1, wn = wave & 1;
  const int fr = lane & 15;
  const int fkc = lane >> 4;
  const int fsw = (fr >> 1) & 3;

  f32x4 acc[4][4] = {};

  const int srow_l = lane >> 2;
  const int schunk = lane & 3;

  auto stage = [&](int buf, int kt) {
    const int k0 = kt * 32;
    #pragma unroll
    for (int i = 0; i < 2; ++i) {
      int rowbase = i * 64 + wave * 16;
      int row = rowbase + srow_l;
      int cg = schunk ^ ((row >> 1) & 3);
      const _Float16* sa = A + (size_t)(m0 + row) * Cc + k0 + cg * 8;
      gl_lds16(sa, &u.s.A[buf][rowbase * 32]);
      const _Float16* sb = W + (size_t)(n0 + row) * Cc + k0 + cg * 8;
      gl_lds16(sb, &u.s.B[buf][rowbase * 32]);
    }
  };

  const int NK = Cc / 32;                     // 16 K-steps
  stage(0, 0);
  stage(1, 1);
  asm volatile("s_waitcnt vmcnt(4)" ::: "memory");
  __builtin_amdgcn_s_barrier();

  int bc = 0, b1 = 1, b2 = 2;
  for (int kt = 0; kt < NK; ++kt) {
    if (kt + 2 < NK) stage(b2, kt + 2);
    half8 af[4], bf[4];
    #pragma unroll
    for (int i = 0; i < 4; ++i) {
      int row = wm * 64 + i * 16 + fr;
      af[i] = *(const half8*)&u.s.A[bc][row * 32 + ((fkc ^ fsw) * 8)];
    }
    #pragma unroll
    for (int j = 0; j < 4; ++j) {
      int row = wn * 64 + j * 16 + fr;
      bf[j] = *(const half8*)&u.s.B[bc][row * 32 + ((fkc ^ fsw) * 8)];
    }
    #pragma unroll
    for (int i = 0; i < 4; ++i)
      #pragma unroll
      for (int j = 0; j < 4; ++j)
        acc[i][j] = __builtin_amdgcn_mfma_f32_16x16x32_f16(af[i], bf[j], acc[i][j], 0, 0, 0);
    if (kt < NK - 1) {
      if (kt + 2 < NK) asm volatile("s_waitcnt vmcnt(4)" ::: "memory");
      else             asm volatile("s_waitcnt vmcnt(0)" ::: "memory");
      __builtin_amdgcn_s_barrier();
    }
    int t0 = bc; bc = b1; b1 = b2; b2 = t0;
  }
  __syncthreads();

  const int bi_o = m0 >> 14, ti_o = (m0 >> 10) & 15, hw0 = m0 & 1023;
  #pragma unroll
  for (int r = 0; r < 2; ++r) {
    if (wm == r) {
      #pragma unroll
      for (int i = 0; i < 4; ++i)
        #pragma unroll
        for (int j = 0; j < 4; ++j)
          #pragma unroll
          for (int jj = 0; jj < 4; ++jj) {
            int row = i * 16 + (lane >> 4) * 4 + jj;
            int col = wn * 64 + j * 16 + (lane & 15);
            u.Cs[row * 129 + col] = acc[i][j][jj];
          }
    }
    __syncthreads();
    if (!PROJ) {
      for (int it = 0; it < 32; ++it) {
        int row = it * 2 + (tid >> 7);
        int col = tid & 127;
        float v = u.Cs[row * 129 + col] + bias[n0 + col];
        Cout[(size_t)(m0 + r * 64 + row) * NCOLS + n0 + col] = (_Float16)v;
      }
    } else {
      for (int it = 0; it < 32; ++it) {
        int col = it * 4 + (tid >> 6);
        int row = tid & 63;
        size_t oidx = (((size_t)(bi_o * Cc + n0 + col) * Tt) + ti_o) * HWn
                      + hw0 + r * 64 + row;
        outF[oidx] = u.Cs[row * 129 + col] + bias[n0 + col] + xres[oidx];
      }
    }
    __syncthreads();
  }
}

// ---------------- K3: attention v2 ----------------
// thread = (qi, hwl); block = (bi, h, 16 hw). Tables fp16 in LDS, row stride
// 72 halves (144B) -> the 4 distinct d-rows per wave hit disjoint bank quads.
// QK via v_dot2_f32_f16 on fp16 regs; PV via packed fp16 FMA; K/V rows
// prefetched one ki ahead (L2-latency hiding).
__global__ __launch_bounds__(256) void attn_k(const _Float16* __restrict__ qkv,  // [M][1536]
                                              const float* __restrict__ ktab,    // [129][64]
                                              const float* __restrict__ vtab,
                                              _Float16* __restrict__ aout) {     // [M][512]
  __shared__ alignas(16) _Float16 kt_s[31 * 72];
  __shared__ alignas(16) _Float16 vt_s[31 * 72];
  int bx = blockIdx.x;                            // grid 1024
  int bi = bx >> 9, h = (bx >> 6) & 7, hwc = bx & 63;
  int t = threadIdx.x;
  int qi = t >> 4, hwl = t & 15;
  int hw = hwc * 16 + hwl;

  for (int i = t; i < 31 * 64; i += 256) {
    int r = i >> 6, c = i & 63;
    kt_s[r * 72 + c] = (_Float16)ktab[(49 + r) * 64 + c];
    vt_s[r * 72 + c] = (_Float16)vtab[(49 + r) * 64 + c];
  }
  __syncthreads();

  size_t mq = ((size_t)(bi * Tt + qi)) * HWn + hw;
  size_t m0 = ((size_t)(bi * Tt + 0)) * HWn + hw;      // ki = 0 row
  const size_t kstride = (size_t)HWn * NQKV;           // ki -> ki+1

  // Q in fp16 registers
  half8 qh[8];
  {
    const _Float16* qrow = qkv + mq * NQKV + h * CHd;
    #pragma unroll
    for (int u = 0; u < 8; ++u) qh[u] = ((const half8*)qrow)[u];
  }

  // ---- K phase ----
  float s[16];
  {
    const _Float16* kp = qkv + m0 * NQKV + Cc + h * CHd;
    half8 kr[8], nx[8];
    #pragma unroll
    for (int u = 0; u < 8; ++u) kr[u] = ((const half8*)kp)[u];
    for (int ki = 0; ki < 16; ++ki) {
      const _Float16* knext = kp + kstride;
      if (ki < 15) {
        #pragma unroll
        for (int u = 0; u < 8; ++u) nx[u] = ((const half8*)knext)[u];
      }
      int d = ki - qi + 15;                       // 0..30
      const _Float16* tp = &kt_s[d * 72];
      float a0 = 0.f, a1 = 0.f, a2 = 0.f, a3 = 0.f;
      #pragma unroll
      for (int u = 0; u < 8; ++u) {
        half8 tv = *(const half8*)(tp + u * 8);
        half8 sm = kr[u] + tv;                    // v_pk_add_f16 x4
        const half2t* s2 = (const half2t*)&sm;
        const half2t* q2 = (const half2t*)&qh[u];
        a0 = fdot2h(q2[0], s2[0], a0);
        a1 = fdot2h(q2[1], s2[1], a1);
        a2 = fdot2h(q2[2], s2[2], a2);
        a3 = fdot2h(q2[3], s2[3], a3);
      }
      s[ki] = ((a0 + a1) + (a2 + a3)) * 0.125f;   // scale^2 = 1/sqrt(64)
      #pragma unroll
      for (int u = 0; u < 8; ++u) kr[u] = nx[u];
      kp = knext;
    }
  }

  // ---- softmax ----
  float mx = s[0];
  #pragma unroll
  for (int ki = 1; ki < 16; ++ki) mx = fmaxf(mx, s[ki]);
  float sum = 0.f;
  #pragma unroll
  for (int ki = 0; ki < 16; ++ki) { s[ki] = __expf(s[ki] - mx); sum += s[ki]; }
  float inv = 1.f / sum;

  // ---- V phase (packed fp16 accumulate) ----
  half8 o8[8];
  #pragma unroll
  for (int u = 0; u < 8; ++u) o8[u] = (half8)(_Float16)0.0f;
  {
    const _Float16* vp = qkv + m0 * NQKV + 2 * Cc + h * CHd;
    half8 vr[8], nx[8];
    #pragma unroll
    for (int u = 0; u < 8; ++u) vr[u] = ((const half8*)vp)[u];
    for (int ki = 0; ki < 16; ++ki) {
      const _Float16* vnext = vp + kstride;
      if (ki < 15) {
        #pragma unroll
        for (int u = 0; u < 8; ++u) nx[u] = ((const half8*)vnext)[u];
      }
      int d = ki - qi + 15;
      const _Float16* tp = &vt_s[d * 72];
      _Float16 ph = (_Float16)s[ki];
      half8 pk8;
      #pragma unroll
      for (int j = 0; j < 8; ++j) pk8[j] = ph;
      #pragma unroll
      for (int u = 0; u < 8; ++u) {
        half8 tv = *(const half8*)(tp + u * 8);
        half8 sm = vr[u] + tv;
        o8[u] += pk8 * sm;                        // v_pk_fma_f16 x4
      }
      #pragma unroll
      for (int u = 0; u < 8; ++u) vr[u] = nx[u];
      vp = vnext;
    }
  }

  _Float16* arow = aout + mq * Cc + h * CHd;
  #pragma unroll
  for (int u = 0; u < 8; ++u) {
    half8 hv;
    #pragma unroll
    for (int c = 0; c < 8; ++c) hv[c] = (_Float16)((float)o8[u][c] * inv);
    *(half8*)(arow + u * 8) = hv;
  }
}

// ---------------- launch ----------------
extern "C" void kernel_launch(void* const* d_in, const int* in_sizes, int n_in,
                              void* d_out, int out_size, void* d_ws, size_t ws_size,
                              hipStream_t stream) {
  const float* x      = (const float*)d_in[0];
  const float* ln_g   = (const float*)d_in[1];
  const float* ln_b   = (const float*)d_in[2];
  const float* qkv_w  = (const float*)d_in[3];
  const float* qkv_b  = (const float*)d_in[4];
  const float* k_tab  = (const float*)d_in[5];
  const float* v_tab  = (const float*)d_in[6];
  const float* proj_w = (const float*)d_in[7];
  const float* proj_b = (const float*)d_in[8];
  float* out = (float*)d_out;

  _Float16* Ah   = (_Float16*)d_ws;                    // [32768][512]
  _Float16* qkvb = Ah   + (size_t)Mtot * Cc;           // [32768][1536]
  _Float16* ab   = qkvb + (size_t)Mtot * NQKV;         // [32768][512]
  _Float16* wq   = ab   + (size_t)Mtot * Cc;           // [1536][512]
  _Float16* wp   = wq   + (size_t)NQKV * Cc;           // [512][512]

  wconv_k<<<3072, 256, 0, stream>>>(qkv_w, proj_w, wq, wp);
  ln_k<<<128, 256, 0, stream>>>(x, ln_g, ln_b, Ah);
  gemm_k<NQKV, false><<<(Mtot / 128) * (NQKV / 128), 256, 0, stream>>>(
      Ah, wq, qkv_b, qkvb, nullptr, nullptr);
  attn_k<<<1024, 256, 0, stream>>>(qkvb, k_tab, v_tab, ab);
  gemm_k<Cc, true><<<(Mtot / 128) * (Cc / 128), 256, 0, stream>>>(
      ab, wp, proj_b, nullptr, x, out);
}

// Round 7
// 408.509 us; speedup vs baseline: 1.2175x; 1.2175x over previous
//
#include <hip/hip_runtime.h>
#include <cstdint>
#include <cstddef>

// ---------------- problem constants (fixed by setup_inputs) ----------------
#define Cc   512        // channels
#define Tt   16         // temporal length
#define HWn  1024       // h*w = 32*32
#define NBat 2          // batch
#define Mtot (NBat*Tt*HWn)   // 32768 sequence rows
#define Hh   8          // heads
#define CHd  64         // head dim
#define NQKV 1536       // 3*C

typedef _Float16 half8  __attribute__((ext_vector_type(8)));
typedef _Float16 half2t __attribute__((ext_vector_type(2)));
typedef float    f32x4  __attribute__((ext_vector_type(4)));

// async global->LDS, 16B per lane; LDS dest = wave-uniform base + lane*16
__device__ __forceinline__ void gl_lds16(const void* g, void* l) {
  __builtin_amdgcn_global_load_lds(
      (const __attribute__((address_space(1))) unsigned int*)g,
      (__attribute__((address_space(3))) unsigned int*)l, 16, 0, 0);
}

__device__ __forceinline__ float fdot2h(half2t a, half2t b, float c) {
#if __has_builtin(__builtin_amdgcn_fdot2)
  return __builtin_amdgcn_fdot2(a, b, c, false);
#else
  return c + (float)a[0] * (float)b[0] + (float)a[1] * (float)b[1];
#endif
}

// ---------------- K0: weights fp32 -> fp16 ----------------
__global__ __launch_bounds__(256) void wconv_k(const float* __restrict__ qw,
                                               const float* __restrict__ pw,
                                               _Float16* __restrict__ wq,
                                               _Float16* __restrict__ wp) {
  int i = blockIdx.x * 256 + threadIdx.x;
  if (i < NQKV * Cc) wq[i] = (_Float16)qw[i];
  if (i < Cc * Cc)   wp[i] = (_Float16)pw[i];
}

// ---------------- K1: LayerNorm -> Ahat fp16 [M][512] ----------------
__global__ __launch_bounds__(256) void ln_k(const float* __restrict__ x,
                                            const float* __restrict__ g,
                                            const float* __restrict__ bln,
                                            _Float16* __restrict__ Ah) {
  int blk = blockIdx.x;                       // 128 blocks
  int bi = blk >> 6, ti = (blk >> 2) & 15, hwc = blk & 3;
  int t = threadIdx.x;
  int hw = hwc * 256 + t;
  const float* xp = x + ((size_t)bi * Cc * Tt + ti) * HWn + hw;
  float s = 0.f, s2 = 0.f;
  #pragma unroll 8
  for (int ci = 0; ci < Cc; ++ci) {
    float v = xp[(size_t)ci * (Tt * HWn)];
    s += v; s2 += v * v;
  }
  float mean = s * (1.f / Cc);
  float var  = s2 * (1.f / Cc) - mean * mean;
  float rs   = rsqrtf(var + 1e-5f);
  size_t m = ((size_t)(bi * Tt + ti)) * HWn + hw;
  _Float16* dst = Ah + m * Cc;
  for (int k0 = 0; k0 < Cc; k0 += 8) {
    half8 hv;
    #pragma unroll
    for (int u = 0; u < 8; ++u) {
      int ci = k0 + u;
      float v = xp[(size_t)ci * (Tt * HWn)];
      hv[u] = (_Float16)((v - mean) * rs * g[ci] + bln[ci]);
    }
    *(half8*)(dst + k0) = hv;
  }
}

// ---------------- K2/K4: fp16 MFMA GEMM (triple-buffered, swizzled) -------
template<int NCOLS, bool PROJ>
__global__ __launch_bounds__(256) void gemm_k(const _Float16* __restrict__ A,
                                              const _Float16* __restrict__ W,
                                              const float* __restrict__ bias,
                                              _Float16* __restrict__ Cout,
                                              const float* __restrict__ xres,
                                              float* __restrict__ outF) {
  __shared__ union {
    struct { _Float16 A[3][128 * 32]; _Float16 B[3][128 * 32]; } s;  // 48 KB
    float Cs[64 * 129];
  } u;

  const int tid  = threadIdx.x;
  const int wave = tid >> 6, lane = tid & 63;
  const int NTN = NCOLS / 128;
  const int tile_m = blockIdx.x / NTN;
  const int tile_n = blockIdx.x % NTN;
  const int m0 = tile_m * 128, n0 = tile_n * 128;
  const int wm = wave >> 1, wn = wave & 1;
  const int fr = lane & 15;
  const int fkc = lane >> 4;
  const int fsw = (fr >> 1) & 3;

  f32x4 acc[4][4] = {};

  const int srow_l = lane >> 2;
  const int schunk = lane & 3;

  auto stage = [&](int buf, int kt) {
    const int k0 = kt * 32;
    #pragma unroll
    for (int i = 0; i < 2; ++i) {
      int rowbase = i * 64 + wave * 16;
      int row = rowbase + srow_l;
      int cg = schunk ^ ((row >> 1) & 3);
      const _Float16* sa = A + (size_t)(m0 + row) * Cc + k0 + cg * 8;
      gl_lds16(sa, &u.s.A[buf][rowbase * 32]);
      const _Float16* sb = W + (size_t)(n0 + row) * Cc + k0 + cg * 8;
      gl_lds16(sb, &u.s.B[buf][rowbase * 32]);
    }
  };

  const int NK = Cc / 32;                     // 16 K-steps
  stage(0, 0);
  stage(1, 1);
  asm volatile("s_waitcnt vmcnt(4)" ::: "memory");
  __builtin_amdgcn_s_barrier();

  int bc = 0, b1 = 1, b2 = 2;
  for (int kt = 0; kt < NK; ++kt) {
    if (kt + 2 < NK) stage(b2, kt + 2);
    half8 af[4], bf[4];
    #pragma unroll
    for (int i = 0; i < 4; ++i) {
      int row = wm * 64 + i * 16 + fr;
      af[i] = *(const half8*)&u.s.A[bc][row * 32 + ((fkc ^ fsw) * 8)];
    }
    #pragma unroll
    for (int j = 0; j < 4; ++j) {
      int row = wn * 64 + j * 16 + fr;
      bf[j] = *(const half8*)&u.s.B[bc][row * 32 + ((fkc ^ fsw) * 8)];
    }
    #pragma unroll
    for (int i = 0; i < 4; ++i)
      #pragma unroll
      for (int j = 0; j < 4; ++j)
        acc[i][j] = __builtin_amdgcn_mfma_f32_16x16x32_f16(af[i], bf[j], acc[i][j], 0, 0, 0);
    if (kt < NK - 1) {
      if (kt + 2 < NK) asm volatile("s_waitcnt vmcnt(4)" ::: "memory");
      else             asm volatile("s_waitcnt vmcnt(0)" ::: "memory");
      __builtin_amdgcn_s_barrier();
    }
    int t0 = bc; bc = b1; b1 = b2; b2 = t0;
  }
  __syncthreads();

  const int bi_o = m0 >> 14, ti_o = (m0 >> 10) & 15, hw0 = m0 & 1023;
  #pragma unroll
  for (int r = 0; r < 2; ++r) {
    if (wm == r) {
      #pragma unroll
      for (int i = 0; i < 4; ++i)
        #pragma unroll
        for (int j = 0; j < 4; ++j)
          #pragma unroll
          for (int jj = 0; jj < 4; ++jj) {
            int row = i * 16 + (lane >> 4) * 4 + jj;
            int col = wn * 64 + j * 16 + (lane & 15);
            u.Cs[row * 129 + col] = acc[i][j][jj];
          }
    }
    __syncthreads();
    if (!PROJ) {
      for (int it = 0; it < 32; ++it) {
        int row = it * 2 + (tid >> 7);
        int col = tid & 127;
        float v = u.Cs[row * 129 + col] + bias[n0 + col];
        Cout[(size_t)(m0 + r * 64 + row) * NCOLS + n0 + col] = (_Float16)v;
      }
    } else {
      for (int it = 0; it < 32; ++it) {
        int col = it * 4 + (tid >> 6);
        int row = tid & 63;
        size_t oidx = (((size_t)(bi_o * Cc + n0 + col) * Tt) + ti_o) * HWn
                      + hw0 + r * 64 + row;
        outF[oidx] = u.Cs[row * 129 + col] + bias[n0 + col] + xres[oidx];
      }
    }
    __syncthreads();
  }
}

// ---------------- K3: attention v3 (LDS-staged K/V, round-2 math) ----------
// block = (bi, h, 16 hw); thread = (qi, hwl). K/V tiles staged cooperatively
// into LDS once per block (kills the 16x per-qi global re-load amplification
// diagnosed in r3). V preloaded to regs before K phase (T14 issue-early).
__global__ __launch_bounds__(256) void attn_k(const _Float16* __restrict__ qkv,  // [M][1536]
                                              const float* __restrict__ ktab,    // [129][64]
                                              const float* __restrict__ vtab,
                                              _Float16* __restrict__ aout) {     // [M][512]
  __shared__ _Float16 kv_s[16 * 16 * 72];        // [ki][hwl][72] K tile, reused for V
  __shared__ _Float16 kt_s[31 * 72];
  __shared__ _Float16 vt_s[31 * 72];

  const int bx = blockIdx.x;                     // grid 1024
  const int bi = bx >> 9, h = (bx >> 6) & 7, hwc = bx & 63;
  const int t = threadIdx.x;
  const int qi = t >> 4, hwl = t & 15;
  const int hw = hwc * 16 + hwl;

  // rel-pos tables -> LDS fp16, stride 72 (the 4 distinct d-rows per wave
  // land on disjoint bank quads; within a quarter-wave the row broadcasts)
  for (int i = t; i < 31 * 64; i += 256) {
    int r = i >> 6, c = i & 63;
    kt_s[r * 72 + c] = (_Float16)ktab[(49 + r) * 64 + c];
    vt_s[r * 72 + c] = (_Float16)vtab[(49 + r) * 64 + c];
  }

  // cooperative K staging: thread (ski, shl) copies one 128B K row
  const int ski = t >> 4, shl = t & 15;
  const _Float16* ksrc = qkv + (((size_t)(bi * Tt + ski)) * HWn + hwc * 16 + shl) * NQKV
                         + Cc + h * CHd;
  _Float16* kdst = &kv_s[(ski * 16 + shl) * 72];
  #pragma unroll
  for (int u = 0; u < 8; ++u)
    *(half8*)(kdst + u * 8) = ((const half8*)ksrc)[u];

  // T14: issue V loads into registers now; written to LDS after K phase
  const _Float16* vsrc = ksrc + Cc;
  half8 vreg[8];
  #pragma unroll
  for (int u = 0; u < 8; ++u) vreg[u] = ((const half8*)vsrc)[u];

  // Q in fp16 registers (per-thread row, read once)
  size_t mq = ((size_t)(bi * Tt + qi)) * HWn + hw;
  const _Float16* qrow = qkv + mq * NQKV + h * CHd;
  half8 qh[8];
  #pragma unroll
  for (int u = 0; u < 8; ++u) qh[u] = ((const half8*)qrow)[u];

  __syncthreads();                               // K tile + tables ready

  // ---- K phase: s[ki] = q . (k + ktab[d]) * scale^2 ----
  float s[16];
  for (int ki = 0; ki < 16; ++ki) {
    int d = ki - qi + 15;                        // 0..30, never clipped (t=16<64)
    const _Float16* kp = &kv_s[(ki * 16 + hwl) * 72];
    const _Float16* tp = &kt_s[d * 72];
    float a0 = 0.f, a1 = 0.f, a2 = 0.f, a3 = 0.f;
    #pragma unroll
    for (int u = 0; u < 8; ++u) {
      half8 kvv = *(const half8*)(kp + u * 8);
      half8 tv  = *(const half8*)(tp + u * 8);
      half8 sm  = kvv + tv;                      // v_pk_add_f16 x4
      const half2t* s2 = (const half2t*)&sm;
      const half2t* q2 = (const half2t*)&qh[u];
      a0 = fdot2h(q2[0], s2[0], a0);
      a1 = fdot2h(q2[1], s2[1], a1);
      a2 = fdot2h(q2[2], s2[2], a2);
      a3 = fdot2h(q2[3], s2[3], a3);
    }
    s[ki] = ((a0 + a1) + (a2 + a3)) * 0.125f;    // 1/sqrt(64)
  }

  // ---- softmax over ki ----
  float mx = s[0];
  #pragma unroll
  for (int ki = 1; ki < 16; ++ki) mx = fmaxf(mx, s[ki]);
  float sum = 0.f;
  #pragma unroll
  for (int ki = 0; ki < 16; ++ki) { s[ki] = __expf(s[ki] - mx); sum += s[ki]; }
  float inv = 1.f / sum;

  __syncthreads();                               // all waves done reading K tile

  // ---- stage V (from preloaded regs) into the same LDS tile ----
  #pragma unroll
  for (int u = 0; u < 8; ++u)
    *(half8*)(kdst + u * 8) = vreg[u];
  __syncthreads();

  // ---- V phase: o += p[ki] * (v + vtab[d]) ----
  half8 o8[8];
  #pragma unroll
  for (int u = 0; u < 8; ++u) o8[u] = (half8)(_Float16)0.0f;
  for (int ki = 0; ki < 16; ++ki) {
    int d = ki - qi + 15;
    const _Float16* vp = &kv_s[(ki * 16 + hwl) * 72];
    const _Float16* tp = &vt_s[d * 72];
    _Float16 ph = (_Float16)s[ki];
    half8 pk8;
    #pragma unroll
    for (int j = 0; j < 8; ++j) pk8[j] = ph;
    #pragma unroll
    for (int u = 0; u < 8; ++u) {
      half8 vr = *(const half8*)(vp + u * 8);
      half8 tv = *(const half8*)(tp + u * 8);
      half8 sm = vr + tv;
      o8[u] += pk8 * sm;                         // v_pk_fma_f16 x4
    }
  }

  _Float16* arow = aout + mq * Cc + h * CHd;
  #pragma unroll
  for (int u = 0; u < 8; ++u) {
    half8 hv;
    #pragma unroll
    for (int c = 0; c < 8; ++c) hv[c] = (_Float16)((float)o8[u][c] * inv);
    *(half8*)(arow + u * 8) = hv;
  }
}

// ---------------- launch ----------------
extern "C" void kernel_launch(void* const* d_in, const int* in_sizes, int n_in,
                              void* d_out, int out_size, void* d_ws, size_t ws_size,
                              hipStream_t stream) {
  const float* x      = (const float*)d_in[0];
  const float* ln_g   = (const float*)d_in[1];
  const float* ln_b   = (const float*)d_in[2];
  const float* qkv_w  = (const float*)d_in[3];
  const float* qkv_b  = (const float*)d_in[4];
  const float* k_tab  = (const float*)d_in[5];
  const float* v_tab  = (const float*)d_in[6];
  const float* proj_w = (const float*)d_in[7];
  const float* proj_b = (const float*)d_in[8];
  float* out = (float*)d_out;

  _Float16* Ah   = (_Float16*)d_ws;                    // [32768][512]
  _Float16* qkvb = Ah   + (size_t)Mtot * Cc;           // [32768][1536]
  _Float16* ab   = qkvb + (size_t)Mtot * NQKV;         // [32768][512]
  _Float16* wq   = ab   + (size_t)Mtot * Cc;           // [1536][512]
  _Float16* wp   = wq   + (size_t)NQKV * Cc;           // [512][512]

  wconv_k<<<3072, 256, 0, stream>>>(qkv_w, proj_w, wq, wp);
  ln_k<<<128, 256, 0, stream>>>(x, ln_g, ln_b, Ah);
  gemm_k<NQKV, false><<<(Mtot / 128) * (NQKV / 128), 256, 0, stream>>>(
      Ah, wq, qkv_b, qkvb, nullptr, nullptr);
  attn_k<<<1024, 256, 0, stream>>>(qkvb, k_tab, v_tab, ab);
  gemm_k<Cc, true><<<(Mtot / 128) * (Cc / 128), 256, 0, stream>>>(
      ab, wp, proj_b, nullptr, x, out);
}